// Round 11
// baseline (392.873 us; speedup 1.0000x reference)
//
#include <hip/hip_runtime.h>

#define B_ 4
#define S_ 2048
#define D_ 1024
#define H_ 16
#define SCALE_ 0.03125f
#define EPS_ 1e-5f
#define NBS_ 8192   // B*S

typedef unsigned short ushort_t;
typedef __attribute__((ext_vector_type(8))) short short8;
typedef __attribute__((ext_vector_type(4))) short short4v;
typedef __attribute__((ext_vector_type(4))) float floatx4;
typedef __attribute__((ext_vector_type(2))) unsigned int uint2v;

__device__ __forceinline__ ushort_t f2bf(float f) {
  union { float f; unsigned u; } v; v.f = f;
  unsigned r = v.u + 0x7fffu + ((v.u >> 16) & 1u);
  return (ushort_t)(r >> 16);
}

__device__ __forceinline__ float fast_exp2(float x) {
#if __has_builtin(__builtin_amdgcn_exp2f)
  return __builtin_amdgcn_exp2f(x);
#else
  return __expf(x * 0.6931471805599453f);
#endif
}

// packed f32x2 -> bf16x2 (RNE), one VALU op; src0 -> low half
__device__ __forceinline__ unsigned cvt_pk_bf16(float a, float b) {
  unsigned r;
  asm("v_cvt_pk_bf16_f32 %0, %1, %2" : "=v"(r) : "v"(a), "v"(b));
  return r;
}

__device__ __forceinline__ short8 cvt8(float4 a, float4 b) {
  short8 r;
  r[0] = (short)f2bf(a.x); r[1] = (short)f2bf(a.y);
  r[2] = (short)f2bf(a.z); r[3] = (short)f2bf(a.w);
  r[4] = (short)f2bf(b.x); r[5] = (short)f2bf(b.y);
  r[6] = (short)f2bf(b.z); r[7] = (short)f2bf(b.w);
  return r;
}

// async global->LDS, 16B per lane; lds dest = wave-uniform base + lane*16
__device__ __forceinline__ void gload16(const void* g, void* l) {
  __builtin_amdgcn_global_load_lds(
      (const __attribute__((address_space(1))) unsigned int*)g,
      (__attribute__((address_space(3))) unsigned int*)l, 16, 0, 0);
}

// ---------------------------------------------------------------------------
// cvtx_k: f32 -> bf16 elementwise (8 elems/thread)
// ---------------------------------------------------------------------------
__global__ __launch_bounds__(256) void cvtx_k(const float* __restrict__ src,
                                              ushort_t* __restrict__ dst)
{
  size_t i = ((size_t)blockIdx.x * 256 + threadIdx.x) * 8;
  float4 a = *(const float4*)(src + i);
  float4 b = *(const float4*)(src + i + 4);
  *(short8*)(dst + i) = cvt8(a, b);
}

// ---------------------------------------------------------------------------
// wtr_all: all four weight transposes in ONE launch (z selects the weight).
// z<3: src = W[h][d][n] ([H,1024,64]) mode0; z==3: src = Wo[c][d] mode1.
// dst layout: N x K, k-contiguous bf16.
// ---------------------------------------------------------------------------
__global__ __launch_bounds__(256) void wtr_all(
    const float* __restrict__ Wq, const float* __restrict__ Wk,
    const float* __restrict__ Wv, const float* __restrict__ Wo,
    ushort_t* __restrict__ wtq, ushort_t* __restrict__ wtk,
    ushort_t* __restrict__ wtv, ushort_t* __restrict__ wto)
{
  __shared__ float t[64][65];
  const int tr = blockIdx.x, tc = blockIdx.y, z = blockIdx.z;
  const float* src; ushort_t* dst; int mode;
  if      (z == 0) { src = Wq; dst = wtq; mode = 0; }
  else if (z == 1) { src = Wk; dst = wtk; mode = 0; }
  else if (z == 2) { src = Wv; dst = wtv; mode = 0; }
  else             { src = Wo; dst = wto; mode = 1; }

  const float* sb; int sld;
  if (mode == 0) { sb = src + (size_t)tr * 65536 + (size_t)tc * 64 * 64; sld = 64; }
  else           { sb = src + (size_t)tc * 64 * 1024 + (size_t)tr * 64;  sld = 1024; }
  const int tid = threadIdx.x;
  const int rr = tid >> 2, cs = (tid & 3) * 16;
  const float* p = sb + (size_t)rr * sld + cs;
#pragma unroll
  for (int j = 0; j < 16; ++j) t[rr][cs + j] = p[j];
  __syncthreads();
  ushort_t* dp = dst + (size_t)(tr * 64 + rr) * 1024 + tc * 64 + cs;
#pragma unroll
  for (int j = 0; j < 16; ++j) dp[j] = f2bf(t[cs + j][rr]);
}

// ---------------------------------------------------------------------------
// XCD-aware tile decode for the 512-block 256x64-tile GEMMs.
// Grid 512 = 32 m-tiles x 16 n-tiles.  Dispatch round-robins id%8 across
// XCDs; decode so XCD x's consecutive queue entries cover all 16 n-tiles
// of ONE m-tile (A-panel 512 KB fetched once per XCD, hit 15 more times):
//   m = (id&7) + 8*(id>>7),  n = (id>>3)&15     (bijective on [0,512))
// ---------------------------------------------------------------------------
__device__ __forceinline__ void xcd_tile2(int id, int& m0, int& n0)
{
  m0 = ((id & 7) + 8 * (id >> 7)) * 256;
  n0 = ((id >> 3) & 15) * 64;
}

// ---------------------------------------------------------------------------
// GEMM mainloop, 256x64 tile (BK=64, dbuf LDS, one barrier/K-step,
// stage-before-compute).  R10 post-mortem: the 128x128 tile stages 32 KB
// per 2.1 MFLOP barrier interval; attn (731 TF) stages 16 KB for the same
// compute.  256x64 doubles arithmetic intensity per staged byte AND per
// barrier: 40 KB (A 32 + B 8) per 4.2 MFLOP.  LDS 80 KB -> exactly
// 2 blocks/CU (160 KB pool).  8 waves = 4M x 2N, 64x32 out each ->
// acc[4][2] (register budget unchanged).  K-order per output identical ->
// bit-identical results.
// LDS kbyte = logical ^ ((row&7)<<4) via pre-swizzled global source.
// ---------------------------------------------------------------------------
__device__ __forceinline__ void gemm_mainloop(
    const ushort_t* __restrict__ A, const ushort_t* __restrict__ Bw,
    ushort_t* As, ushort_t* Bs,   // As[2][256][64] (64KB), Bs[2][64][64] (16KB)
    int m0, int n0, int wv, int lane, floatx4 acc[4][2])
{
  const int quad = lane >> 4, l16 = lane & 15;
  const int wm = wv & 3, wn = wv >> 2;
  const int r8 = lane >> 3;                 // row within 8-row group
  const int kx = ((lane & 7) ^ r8) * 8;     // pre-swizzled k-elem offset

  auto stage = [&](int buf, int k0) {
#pragma unroll
    for (int j = 0; j < 4; ++j) {
      const int rb = (wv * 4 + j) * 8;      // A rows: 8 per gload16, [0,256)
      gload16(A + (size_t)(m0 + rb + r8) * 1024 + k0 + kx,
              (char*)As + buf * 32768 + rb * 128);
    }
    const int rbB = wv * 8;                 // B rows: [0,64)
    gload16(Bw + (size_t)(n0 + rbB + r8) * 1024 + k0 + kx,
            (char*)Bs + buf * 8192 + rbB * 128);
  };

  stage(0, 0);
  __syncthreads();    // implicit vmcnt(0) drain

  const int swz = (l16 & 7) << 4;
  for (int it = 0; it < 16; ++it) {
    const int cur = it & 1;
    if (it < 15) stage(cur ^ 1, (it + 1) * 64);
    const char* Ab = (const char*)As + cur * 32768;
    const char* Bb = (const char*)Bs + cur * 8192;
#pragma unroll
    for (int hf = 0; hf < 2; ++hf) {
      short8 af[4], bf[2];
      const int C = (hf * 64 + quad * 16) ^ swz;
#pragma unroll
      for (int i = 0; i < 4; ++i)
        af[i] = *(const short8*)(Ab + (wm * 64 + i * 16 + l16) * 128 + C);
#pragma unroll
      for (int i = 0; i < 2; ++i)
        bf[i] = *(const short8*)(Bb + (wn * 32 + i * 16 + l16) * 128 + C);
#pragma unroll
      for (int mi = 0; mi < 4; ++mi)
#pragma unroll
        for (int ni = 0; ni < 2; ++ni)
          acc[mi][ni] = __builtin_amdgcn_mfma_f32_16x16x32_bf16(
              af[mi], bf[ni], acc[mi][ni], 0, 0, 0);
    }
    __syncthreads();  // drains prefetch + LDS reads; protects buffer reuse
  }
}

// ---------------------------------------------------------------------------
// gemm_proj: C[m][c] = (A[m][:].Bw[c][:] + bias[c]) * scale -> [B][H][S][64]
// 256|2048 so a block never crosses a batch boundary.
// ---------------------------------------------------------------------------
__global__ __launch_bounds__(512, 4) void gemm_proj(
    const ushort_t* __restrict__ A, const ushort_t* __restrict__ Bw,
    const float* __restrict__ bias, ushort_t* __restrict__ outp, float scale)
{
  __shared__ ushort_t As[2 * 256 * 64];
  __shared__ ushort_t Bs[2 * 64 * 64];
  const int tid = threadIdx.x;
  const int wv = tid >> 6, lane = tid & 63, quad = lane >> 4, l16 = lane & 15;
  int m0, n0;
  xcd_tile2(blockIdx.x, m0, n0);
  const int wm = wv & 3, wn = wv >> 2;

  floatx4 acc[4][2];
#pragma unroll
  for (int i = 0; i < 4; ++i)
#pragma unroll
    for (int j = 0; j < 2; ++j) acc[i][j] = (floatx4){0.f, 0.f, 0.f, 0.f};

  gemm_mainloop(A, Bw, As, Bs, m0, n0, wv, lane, acc);

  const int b = m0 >> 11;
  const int sbase = (m0 & 2047) + wm * 64;
#pragma unroll
  for (int ni = 0; ni < 2; ++ni) {
    const int c = n0 + wn * 32 + ni * 16 + l16;
    const int h = c >> 6, nn = c & 63;
    const float bs = bias[c];
    ushort_t* op = outp + (size_t)(b * 16 + h) * 2048 * 64 + nn;
#pragma unroll
    for (int mi = 0; mi < 4; ++mi)
#pragma unroll
      for (int r = 0; r < 4; ++r) {
        int s = sbase + mi * 16 + quad * 4 + r;
        op[(size_t)s * 64] = f2bf((acc[mi][ni][r] + bs) * scale);
      }
  }
}

// ---------------------------------------------------------------------------
// gemm_projT: same GEMM but epilogue writes V^T: out[(b*16+h)][dv][s]
// ---------------------------------------------------------------------------
__global__ __launch_bounds__(512, 4) void gemm_projT(
    const ushort_t* __restrict__ A, const ushort_t* __restrict__ Bw,
    const float* __restrict__ bias, ushort_t* __restrict__ outp)
{
  __shared__ ushort_t As[2 * 256 * 64];
  __shared__ ushort_t Bs[2 * 64 * 64];
  const int tid = threadIdx.x;
  const int wv = tid >> 6, lane = tid & 63, quad = lane >> 4, l16 = lane & 15;
  int m0, n0;
  xcd_tile2(blockIdx.x, m0, n0);
  const int wm = wv & 3, wn = wv >> 2;

  floatx4 acc[4][2];
#pragma unroll
  for (int i = 0; i < 4; ++i)
#pragma unroll
    for (int j = 0; j < 2; ++j) acc[i][j] = (floatx4){0.f, 0.f, 0.f, 0.f};

  gemm_mainloop(A, Bw, As, Bs, m0, n0, wv, lane, acc);

  const int b = m0 >> 11;
  const int sbase = (m0 & 2047) + wm * 64;
#pragma unroll
  for (int ni = 0; ni < 2; ++ni) {
    const int c = n0 + wn * 32 + ni * 16 + l16;
    const int h = c >> 6, nn = c & 63;
    const float bs = bias[c];
    ushort_t* op = outp + ((size_t)(b * 16 + h) * 64 + nn) * 2048;
#pragma unroll
    for (int mi = 0; mi < 4; ++mi) {
      int s0v = sbase + mi * 16 + quad * 4;
      short4v p;
#pragma unroll
      for (int r = 0; r < 4; ++r) p[r] = (short)f2bf(acc[mi][ni][r] + bs);
      *(short4v*)(op + s0v) = p;
    }
  }
}

// ---------------------------------------------------------------------------
// gemm_oproj: y[m][d] = ao[m][:].Wt_o[d][:] + bo[d] + resid[m][d]  (f32 out)
// Fused batch-stats: per-channel sum/sumsq via quad shuffle-reduce + one
// atomicAdd per column per wave (4 m-waves each add their 64-row partial).
// ---------------------------------------------------------------------------
__global__ __launch_bounds__(512, 4) void gemm_oproj(
    const ushort_t* __restrict__ A, const ushort_t* __restrict__ Bw,
    const float* __restrict__ bo, const float* __restrict__ resid,
    float* __restrict__ y, float* __restrict__ s1, float* __restrict__ s2)
{
  __shared__ ushort_t As[2 * 256 * 64];
  __shared__ ushort_t Bs[2 * 64 * 64];
  const int tid = threadIdx.x;
  const int wv = tid >> 6, lane = tid & 63, quad = lane >> 4, l16 = lane & 15;
  int m0, n0;
  xcd_tile2(blockIdx.x, m0, n0);
  const int wm = wv & 3, wn = wv >> 2;

  floatx4 acc[4][2];
#pragma unroll
  for (int i = 0; i < 4; ++i)
#pragma unroll
    for (int j = 0; j < 2; ++j) acc[i][j] = (floatx4){0.f, 0.f, 0.f, 0.f};

  gemm_mainloop(A, Bw, As, Bs, m0, n0, wv, lane, acc);

  const int mb = m0 + wm * 64;
#pragma unroll
  for (int ni = 0; ni < 2; ++ni) {
    const int d = n0 + wn * 32 + ni * 16 + l16;
    const float bs = bo[d];
    float ps1 = 0.f, ps2 = 0.f;
#pragma unroll
    for (int mi = 0; mi < 4; ++mi)
#pragma unroll
      for (int r = 0; r < 4; ++r) {
        int m = mb + mi * 16 + quad * 4 + r;
        float val = acc[mi][ni][r] + bs + resid[(size_t)m * 1024 + d];
        y[(size_t)m * 1024 + d] = val;
        ps1 += val;
        ps2 += val * val;
      }
    ps1 += __shfl_xor(ps1, 16); ps1 += __shfl_xor(ps1, 32);
    ps2 += __shfl_xor(ps2, 16); ps2 += __shfl_xor(ps2, 32);
    if (quad == 0) {
      atomicAdd(&s1[d], ps1);
      atomicAdd(&s2[d], ps2);
    }
  }
}

// ---------------------------------------------------------------------------
// attn_k v9 (frozen at R10 state): swapped QK^T, cvt_pk pack, conflict-free
// P swizzle, ones-MFMA row-sum, single-slot P, per-rb register diet
// (live set ~112, VGPR 64, no spills), XCD-aware block decode.
// Known state: 93.5 us, 731 TF effective, FETCH 24.6 MB, occupancy 35%.
// LDS byte map: K dbuf [0,16384) | V dbuf [16384,32768) | P [32768,40960)
// ---------------------------------------------------------------------------
__global__ __launch_bounds__(256, 4) void attn_k(
    const ushort_t* __restrict__ q, const ushort_t* __restrict__ k,
    const ushort_t* __restrict__ vt, ushort_t* __restrict__ ao)
{
  __shared__ ushort_t lds[20480];   // 40 KiB
  char* ldsb = (char*)lds;
  const int tid = threadIdx.x;
  const int wv = tid >> 6, lane = tid & 63, quad = lane >> 4, l16 = lane & 15;

  const int id = blockIdx.x;
  const int j = id >> 3;
  const int pair = (id & 7) + 8 * (j >> 4);      // b*16 + h
  const int q0 = (j & 15) * 128;
  const int h = pair & 15, b = pair >> 4;

  const size_t bh = (size_t)(b * H_ + h) * S_;
  const ushort_t* vb = vt + (size_t)(b * H_ + h) * 64 * S_;

  short8 aq[2][2];
#pragma unroll
  for (int rb = 0; rb < 2; ++rb) {
    const ushort_t* qrow = q + (bh + q0 + wv * 32 + rb * 16 + l16) * 64;
    aq[rb][0] = *(const short8*)(qrow + quad * 8);
    aq[rb][1] = *(const short8*)(qrow + 32 + quad * 8);
  }

  short8 ones;
#pragma unroll
  for (int j2 = 0; j2 < 8; ++j2) ones[j2] = (short)0x3F80;

  floatx4 o[2][4];
  floatx4 accl[2];
#pragma unroll
  for (int rb = 0; rb < 2; ++rb) {
#pragma unroll
    for (int cb = 0; cb < 4; ++cb) o[rb][cb] = (floatx4){0.f, 0.f, 0.f, 0.f};
    accl[rb] = (floatx4){0.f, 0.f, 0.f, 0.f};
  }

  const int swz = ((l16 & 7) << 4) | (l16 & 8);
  const int q8 = quad * 8;
  const int pb = 32768 + wv * 2048 + l16 * 128;

  auto stage = [&](int nb, int t0) {
#pragma unroll
    for (int i = 0; i < 4; ++i) {
      const int idx = wv * 4 + i;
      const int cb = (idx >> 1) & 3, hf = idx & 1;
      if (idx < 8)
        gload16(k + (bh + t0 + cb * 16 + l16) * 64 + hf * 32 + quad * 8,
                (char*)lds + nb * 8192 + idx * 1024);
      else
        gload16(vb + (size_t)(cb * 16 + l16) * S_ + t0 + hf * 32 + quad * 8,
                (char*)lds + 16384 + nb * 8192 + (idx - 8) * 1024);
    }
  };

  stage(0, 0);
  asm volatile("s_waitcnt vmcnt(0)" ::: "memory");
  __syncthreads();

  for (int t0 = 0; t0 < S_; t0 += 64) {
    const int nb = (t0 >> 6) & 1;
    const ushort_t* KsC = lds + nb * 4096;
    const ushort_t* VsC = lds + 8192 + nb * 4096;
    if (t0 + 64 < S_) stage(nb ^ 1, t0 + 64);

    // per-rb: QK^T -> exp2 + pack -> P write -> PV  (single P slot; DS ops
    // are wave-in-order so rb1 writes cannot pass rb0 reads)
#pragma unroll
    for (int rb = 0; rb < 2; ++rb) {
      floatx4 sc[4];
#pragma unroll
      for (int cb = 0; cb < 4; ++cb) sc[cb] = (floatx4){0.f, 0.f, 0.f, 0.f};
      __builtin_amdgcn_s_setprio(1);
#pragma unroll
      for (int hf = 0; hf < 2; ++hf) {
        short8 bk[4];
#pragma unroll
        for (int cb = 0; cb < 4; ++cb)
          bk[cb] = *(const short8*)&KsC[(cb * 2 + hf) * 512 + lane * 8];
#pragma unroll
        for (int cb = 0; cb < 4; ++cb)
          sc[cb] = __builtin_amdgcn_mfma_f32_16x16x32_bf16(
              bk[cb], aq[rb][hf], sc[cb], 0, 0, 0);
      }
      __builtin_amdgcn_s_setprio(0);

#pragma unroll
      for (int cb = 0; cb < 4; ++cb) {
        float p0 = fast_exp2(sc[cb][0]);
        float p1 = fast_exp2(sc[cb][1]);
        float p2 = fast_exp2(sc[cb][2]);
        float p3 = fast_exp2(sc[cb][3]);
        uint2v w;
        w[0] = cvt_pk_bf16(p0, p1);
        w[1] = cvt_pk_bf16(p2, p3);
        *(uint2v*)(ldsb + pb + ((cb * 32 + q8) ^ swz)) = w;
      }
      asm volatile("s_waitcnt lgkmcnt(0)" ::: "memory");
      __builtin_amdgcn_sched_barrier(0);

      __builtin_amdgcn_s_setprio(1);
#pragma unroll
      for (int hf = 0; hf < 2; ++hf) {
        short8 bvf[4];
#pragma unroll
        for (int cb = 0; cb < 4; ++cb)
          bvf[cb] = *(const short8*)&VsC[(cb * 2 + hf) * 512 + lane * 8];
        const int lo = (hf * 64 + quad * 16) ^ swz;
        short4v a0 = *(const short4v*)(ldsb + pb + lo);
        short4v a1 = *(const short4v*)(ldsb + pb + (lo ^ 8));
        short8 ap;
        ap[0] = a0[0]; ap[1] = a0[1]; ap[2] = a0[2]; ap[3] = a0[3];
        ap[4] = a1[0]; ap[5] = a1[1]; ap[6] = a1[2]; ap[7] = a1[3];
#pragma unroll
        for (int cb = 0; cb < 4; ++cb)
          o[rb][cb] = __builtin_amdgcn_mfma_f32_16x16x32_bf16(
              ap, bvf[cb], o[rb][cb], 0, 0, 0);
        accl[rb] = __builtin_amdgcn_mfma_f32_16x16x32_bf16(
            ap, ones, accl[rb], 0, 0, 0);
      }
      __builtin_amdgcn_s_setprio(0);
    }

    asm volatile("s_waitcnt vmcnt(0)" ::: "memory");  // prefetch landed
    __syncthreads();
  }

  float linv[2][4];
#pragma unroll
  for (int rb = 0; rb < 2; ++rb)
#pragma unroll
    for (int r = 0; r < 4; ++r)
      linv[rb][r] = 1.f / accl[rb][r];
#pragma unroll
  for (int rb = 0; rb < 2; ++rb)
#pragma unroll
    for (int cb = 0; cb < 4; ++cb)
#pragma unroll
      for (int r = 0; r < 4; ++r) {
        float val = o[rb][cb][r] * linv[rb][r];
        size_t idx = (size_t)(b * S_ + q0 + wv * 32 + rb * 16 + quad * 4 + r) * 1024
                     + h * 64 + cb * 16 + l16;
        ao[idx] = f2bf(val);
      }
}

// ---------------------------------------------------------------------------
// K5: batchnorm affine + 64x64 transpose -> out[b][d][s] (f32)
// ---------------------------------------------------------------------------
__global__ __launch_bounds__(256) void norm_k(
    const float* __restrict__ y, const float* __restrict__ s1,
    const float* __restrict__ s2, const float* __restrict__ gamma,
    const float* __restrict__ beta, float* __restrict__ out)
{
  __shared__ float tile[64][65];
  __shared__ float scl[64], sft[64];
  const int tid = threadIdx.x;
  const int s0 = blockIdx.x * 64, d0 = blockIdx.y * 64, b = blockIdx.z;

  if (tid < 64) {
    int d = d0 + tid;
    float mean = s1[d] * (1.f / (float)NBS_);
    float var = s2[d] * (1.f / (float)NBS_) - mean * mean;
    float rstd = rsqrtf(var + EPS_);
    float g = gamma[d];
    scl[tid] = rstd * g;
    sft[tid] = beta[d] - mean * rstd * g;
  }
  __syncthreads();

  const int si = tid >> 2, dc = (tid & 3) * 16;
  const float* row = y + (size_t)(b * S_ + s0 + si) * D_ + d0 + dc;
#pragma unroll
  for (int j = 0; j < 16; ++j)
    tile[si][dc + j] = row[j] * scl[dc + j] + sft[dc + j];
  __syncthreads();

  const int di = tid >> 2, sg = (tid & 3) * 16;
  float* dst = out + (size_t)(b * D_ + d0 + di) * S_ + s0 + sg;
#pragma unroll
  for (int jj = 0; jj < 4; ++jj) {
    float4 p;
    p.x = tile[sg + jj * 4 + 0][di];
    p.y = tile[sg + jj * 4 + 1][di];
    p.z = tile[sg + jj * 4 + 2][di];
    p.w = tile[sg + jj * 4 + 3][di];
    *(float4*)(dst + jj * 4) = p;
  }
}

// ---------------------------------------------------------------------------
extern "C" void kernel_launch(void* const* d_in, const int* in_sizes, int n_in,
                              void* d_out, int out_size, void* d_ws, size_t ws_size,
                              hipStream_t stream)
{
  (void)in_sizes; (void)n_in; (void)out_size; (void)ws_size;
  const float* Q     = (const float*)d_in[0];
  const float* Kin   = (const float*)d_in[1];
  const float* Vin   = (const float*)d_in[2];
  const float* Wq    = (const float*)d_in[3];
  const float* bq    = (const float*)d_in[4];
  const float* Wk    = (const float*)d_in[5];
  const float* bk    = (const float*)d_in[6];
  const float* Wv    = (const float*)d_in[7];
  const float* bv    = (const float*)d_in[8];
  const float* Wo    = (const float*)d_in[9];
  const float* bo    = (const float*)d_in[10];
  const float* gamma = (const float*)d_in[11];
  const float* beta  = (const float*)d_in[12];
  float* out = (float*)d_out;

  char* ws = (char*)d_ws;
  const size_t MB = 1u << 20;
  ushort_t* xb  = (ushort_t*)(ws);
  ushort_t* wtq = (ushort_t*)(ws + 16 * MB);
  ushort_t* wtk = (ushort_t*)(ws + 18 * MB);
  ushort_t* wtv = (ushort_t*)(ws + 20 * MB);
  ushort_t* wto = (ushort_t*)(ws + 22 * MB);
  ushort_t* qb  = (ushort_t*)(ws + 24 * MB);
  ushort_t* kb  = (ushort_t*)(ws + 40 * MB);
  ushort_t* vtb = (ushort_t*)(ws + 56 * MB);
  ushort_t* ao  = (ushort_t*)(ws);
  float*    y   = (float*)(ws + 24 * MB);
  float*    s1  = (float*)(ws + 56 * MB);
  float*    s2  = (float*)(ws + 56 * MB + 4096);

  // all 4 weight transposes in one launch
  wtr_all<<<dim3(16, 16, 4), 256, 0, stream>>>(Wq, Wk, Wv, Wo,
                                               wtq, wtk, wtv, wto);

  // q pre-scaled by SCALE*log2(e) so attention logits are exp2-domain
  const float QSC = SCALE_ * 1.44269504088896f;
  cvtx_k<<<4096, 256, 0, stream>>>(Q, xb);
  gemm_proj<<<512, 512, 0, stream>>>(xb, wtq, bq, qb, QSC);
  cvtx_k<<<4096, 256, 0, stream>>>(Kin, xb);
  gemm_proj<<<512, 512, 0, stream>>>(xb, wtk, bk, kb, 1.0f);
  cvtx_k<<<4096, 256, 0, stream>>>(Vin, xb);
  gemm_projT<<<512, 512, 0, stream>>>(xb, wtv, bv, vtb);

  attn_k<<<1024, 256, 0, stream>>>(qb, kb, vtb, ao);

  // s1/s2 overlap vtb (dead after attn_k); zero them before fused oproj
  hipMemsetAsync(ws + 56 * MB, 0, 8192, stream);
  gemm_oproj<<<512, 512, 0, stream>>>(ao, wto, bo, Q, y, s1, s2);

  norm_k<<<dim3(32, 16, 4), 256, 0, stream>>>(y, s1, s2, gamma, beta, out);
}

// Round 12
// 370.566 us; speedup vs baseline: 1.0602x; 1.0602x over previous
//
#include <hip/hip_runtime.h>

#define B_ 4
#define S_ 2048
#define D_ 1024
#define H_ 16
#define SCALE_ 0.03125f
#define EPS_ 1e-5f
#define NBS_ 8192   // B*S

typedef unsigned short ushort_t;
typedef __attribute__((ext_vector_type(8))) short short8;
typedef __attribute__((ext_vector_type(4))) short short4v;
typedef __attribute__((ext_vector_type(4))) float floatx4;
typedef __attribute__((ext_vector_type(2))) unsigned int uint2v;

__device__ __forceinline__ ushort_t f2bf(float f) {
  union { float f; unsigned u; } v; v.f = f;
  unsigned r = v.u + 0x7fffu + ((v.u >> 16) & 1u);
  return (ushort_t)(r >> 16);
}

__device__ __forceinline__ float fast_exp2(float x) {
#if __has_builtin(__builtin_amdgcn_exp2f)
  return __builtin_amdgcn_exp2f(x);
#else
  return __expf(x * 0.6931471805599453f);
#endif
}

// packed f32x2 -> bf16x2 (RNE), one VALU op; src0 -> low half
__device__ __forceinline__ unsigned cvt_pk_bf16(float a, float b) {
  unsigned r;
  asm("v_cvt_pk_bf16_f32 %0, %1, %2" : "=v"(r) : "v"(a), "v"(b));
  return r;
}

__device__ __forceinline__ short8 cvt8(float4 a, float4 b) {
  short8 r;
  r[0] = (short)f2bf(a.x); r[1] = (short)f2bf(a.y);
  r[2] = (short)f2bf(a.z); r[3] = (short)f2bf(a.w);
  r[4] = (short)f2bf(b.x); r[5] = (short)f2bf(b.y);
  r[6] = (short)f2bf(b.z); r[7] = (short)f2bf(b.w);
  return r;
}

// async global->LDS, 16B per lane; lds dest = wave-uniform base + lane*16
__device__ __forceinline__ void gload16(const void* g, void* l) {
  __builtin_amdgcn_global_load_lds(
      (const __attribute__((address_space(1))) unsigned int*)g,
      (__attribute__((address_space(3))) unsigned int*)l, 16, 0, 0);
}

// ---------------------------------------------------------------------------
// cvtx3_k: f32 -> bf16, up to 3 tensors in one launch.  z = blockIdx>>12
// selects the (src,dst) pair; narrow path passes identical pointers and
// launches 4096 blocks (z=0).
// ---------------------------------------------------------------------------
__global__ __launch_bounds__(256) void cvtx3_k(
    const float* __restrict__ s0, const float* __restrict__ s1,
    const float* __restrict__ s2,
    ushort_t* __restrict__ d0, ushort_t* __restrict__ d1,
    ushort_t* __restrict__ d2)
{
  const int z = blockIdx.x >> 12;
  const int blk = blockIdx.x & 4095;
  const float* src = z == 0 ? s0 : (z == 1 ? s1 : s2);
  ushort_t* dst = z == 0 ? d0 : (z == 1 ? d1 : d2);
  size_t i = ((size_t)blk * 256 + threadIdx.x) * 8;
  float4 a = *(const float4*)(src + i);
  float4 b = *(const float4*)(src + i + 4);
  *(short8*)(dst + i) = cvt8(a, b);
}

// ---------------------------------------------------------------------------
// wtr_all: all four weight transposes in ONE launch (z selects the weight).
// z<3: src = W[h][d][n] ([H,1024,64]) mode0; z==3: src = Wo[c][d] mode1.
// dst layout: N x K, k-contiguous bf16.
// ---------------------------------------------------------------------------
__global__ __launch_bounds__(256) void wtr_all(
    const float* __restrict__ Wq, const float* __restrict__ Wk,
    const float* __restrict__ Wv, const float* __restrict__ Wo,
    ushort_t* __restrict__ wtq, ushort_t* __restrict__ wtk,
    ushort_t* __restrict__ wtv, ushort_t* __restrict__ wto)
{
  __shared__ float t[64][65];
  const int tr = blockIdx.x, tc = blockIdx.y, z = blockIdx.z;
  const float* src; ushort_t* dst; int mode;
  if      (z == 0) { src = Wq; dst = wtq; mode = 0; }
  else if (z == 1) { src = Wk; dst = wtk; mode = 0; }
  else if (z == 2) { src = Wv; dst = wtv; mode = 0; }
  else             { src = Wo; dst = wto; mode = 1; }

  const float* sb; int sld;
  if (mode == 0) { sb = src + (size_t)tr * 65536 + (size_t)tc * 64 * 64; sld = 64; }
  else           { sb = src + (size_t)tc * 64 * 1024 + (size_t)tr * 64;  sld = 1024; }
  const int tid = threadIdx.x;
  const int rr = tid >> 2, cs = (tid & 3) * 16;
  const float* p = sb + (size_t)rr * sld + cs;
#pragma unroll
  for (int j = 0; j < 16; ++j) t[rr][cs + j] = p[j];
  __syncthreads();
  ushort_t* dp = dst + (size_t)(tr * 64 + rr) * 1024 + tc * 64 + cs;
#pragma unroll
  for (int j = 0; j < 16; ++j) dp[j] = f2bf(t[cs + j][rr]);
}

// ---------------------------------------------------------------------------
// XCD-aware tile decode for 512-block 128x128-tile GEMM slices.
//   m = (id&7) + 8*(id>>6),  n = (id>>3)&7     (bijective on [0,512))
// ---------------------------------------------------------------------------
__device__ __forceinline__ void xcd_tile(int id, int& m0, int& n0)
{
  m0 = ((id & 7) + 8 * (id >> 6)) * 128;
  n0 = ((id >> 3) & 7) * 128;
}

// ---------------------------------------------------------------------------
// Shared GEMM mainloop (R10 config, measured best): 128x128 tile, BK=64,
// dbuf LDS (64 KB), one barrier/K-step, stage-before-compute.  8 waves
// (512 thr): wave (wm,wn)=(wv&1,wv>>1) owns 64x32 -> acc[4][2].
// LDS kbyte = logical ^ ((row&7)<<4) via pre-swizzled global source.
// ---------------------------------------------------------------------------
__device__ __forceinline__ void gemm_mainloop(
    const ushort_t* __restrict__ A, const ushort_t* __restrict__ Bw,
    ushort_t* As, ushort_t* Bs,   // each [2][128*64] elems (32 KiB)
    int m0, int n0, int wv, int lane, floatx4 acc[4][2])
{
  const int quad = lane >> 4, l16 = lane & 15;
  const int wm = wv & 1, wn = wv >> 1;
  const int r8 = lane >> 3;                 // row within 8-row group
  const int kx = ((lane & 7) ^ r8) * 8;     // pre-swizzled k-elem offset

  auto stage = [&](int buf, int k0) {
#pragma unroll
    for (int j = 0; j < 2; ++j) {
      const int rb = (wv * 2 + j) * 8;      // 8 rows per gload16
      gload16(A + (size_t)(m0 + rb + r8) * 1024 + k0 + kx,
              (char*)As + buf * 16384 + rb * 128);
      gload16(Bw + (size_t)(n0 + rb + r8) * 1024 + k0 + kx,
              (char*)Bs + buf * 16384 + rb * 128);
    }
  };

  stage(0, 0);
  __syncthreads();    // implicit vmcnt(0) drain

  const int swz = (l16 & 7) << 4;
  for (int it = 0; it < 16; ++it) {
    const int cur = it & 1;
    if (it < 15) stage(cur ^ 1, (it + 1) * 64);
    const char* Ab = (const char*)As + cur * 16384;
    const char* Bb = (const char*)Bs + cur * 16384;
#pragma unroll
    for (int hf = 0; hf < 2; ++hf) {
      short8 af[4], bf[2];
      const int C = (hf * 64 + quad * 16) ^ swz;
#pragma unroll
      for (int i = 0; i < 4; ++i)
        af[i] = *(const short8*)(Ab + (wm * 64 + i * 16 + l16) * 128 + C);
#pragma unroll
      for (int i = 0; i < 2; ++i)
        bf[i] = *(const short8*)(Bb + (wn * 32 + i * 16 + l16) * 128 + C);
#pragma unroll
      for (int mi = 0; mi < 4; ++mi)
#pragma unroll
        for (int ni = 0; ni < 2; ++ni)
          acc[mi][ni] = __builtin_amdgcn_mfma_f32_16x16x32_bf16(
              af[mi], bf[ni], acc[mi][ni], 0, 0, 0);
    }
    __syncthreads();  // drains prefetch + LDS reads; protects buffer reuse
  }
}

// ---------------------------------------------------------------------------
// gemm_proj3: Q/K/V projections in ONE launch.  z = zbase + (blockIdx>>9)
// selects {A, W, bias, out, scale, epilogue}.  z<2: standard epilogue into
// [B][H][S][64] (z==0 applies qsc); z==2: V^T epilogue into
// [(b*16+h)][dv][s].  Each 512-block slice keeps the XCD decode (512%8==0).
// ---------------------------------------------------------------------------
__global__ __launch_bounds__(512, 4) void gemm_proj3(
    const ushort_t* __restrict__ xq, const ushort_t* __restrict__ xk,
    const ushort_t* __restrict__ xv,
    const ushort_t* __restrict__ wtq, const ushort_t* __restrict__ wtk,
    const ushort_t* __restrict__ wtv,
    const float* __restrict__ bq, const float* __restrict__ bk,
    const float* __restrict__ bv,
    ushort_t* __restrict__ oq, ushort_t* __restrict__ ok,
    ushort_t* __restrict__ ov, float qsc, int zbase)
{
  __shared__ ushort_t As[2 * 128 * 64];
  __shared__ ushort_t Bs[2 * 128 * 64];
  const int tid = threadIdx.x;
  const int wv = tid >> 6, lane = tid & 63, quad = lane >> 4, l16 = lane & 15;
  const int z = zbase + (blockIdx.x >> 9);
  int m0, n0;
  xcd_tile(blockIdx.x & 511, m0, n0);
  const int wm = wv & 1, wn = wv >> 1;

  const ushort_t* A  = z == 0 ? xq  : (z == 1 ? xk  : xv);
  const ushort_t* Bw = z == 0 ? wtq : (z == 1 ? wtk : wtv);
  const float* bias  = z == 0 ? bq  : (z == 1 ? bk  : bv);

  floatx4 acc[4][2];
#pragma unroll
  for (int i = 0; i < 4; ++i)
#pragma unroll
    for (int j = 0; j < 2; ++j) acc[i][j] = (floatx4){0.f, 0.f, 0.f, 0.f};

  gemm_mainloop(A, Bw, As, Bs, m0, n0, wv, lane, acc);

  const int b = m0 >> 11;
  const int sbase = (m0 & 2047) + wm * 64;
  if (z < 2) {
    ushort_t* outp = z == 0 ? oq : ok;
    const float scale = z == 0 ? qsc : 1.0f;
#pragma unroll
    for (int ni = 0; ni < 2; ++ni) {
      const int c = n0 + wn * 32 + ni * 16 + l16;
      const int h = c >> 6, nn = c & 63;
      const float bs = bias[c];
      ushort_t* op = outp + (size_t)(b * 16 + h) * 2048 * 64 + nn;
#pragma unroll
      for (int mi = 0; mi < 4; ++mi)
#pragma unroll
        for (int r = 0; r < 4; ++r) {
          int s = sbase + mi * 16 + quad * 4 + r;
          op[(size_t)s * 64] = f2bf((acc[mi][ni][r] + bs) * scale);
        }
    }
  } else {
#pragma unroll
    for (int ni = 0; ni < 2; ++ni) {
      const int c = n0 + wn * 32 + ni * 16 + l16;
      const int h = c >> 6, nn = c & 63;
      const float bs = bias[c];
      ushort_t* op = ov + ((size_t)(b * 16 + h) * 64 + nn) * 2048;
#pragma unroll
      for (int mi = 0; mi < 4; ++mi) {
        int s0v = sbase + mi * 16 + quad * 4;
        short4v p;
#pragma unroll
        for (int r = 0; r < 4; ++r) p[r] = (short)f2bf(acc[mi][ni][r] + bs);
        *(short4v*)(op + s0v) = p;
      }
    }
  }
}

// ---------------------------------------------------------------------------
// gemm_oproj: y[m][d] = ao[m][:].Wt_o[d][:] + bo[d] + resid[m][d]  (f32 out)
// Fused batch-stats: per-channel sum/sumsq via quad shuffle-reduce + one
// atomicAdd per column per wave.
// ---------------------------------------------------------------------------
__global__ __launch_bounds__(512, 4) void gemm_oproj(
    const ushort_t* __restrict__ A, const ushort_t* __restrict__ Bw,
    const float* __restrict__ bo, const float* __restrict__ resid,
    float* __restrict__ y, float* __restrict__ s1, float* __restrict__ s2)
{
  __shared__ ushort_t As[2 * 128 * 64];
  __shared__ ushort_t Bs[2 * 128 * 64];
  const int tid = threadIdx.x;
  const int wv = tid >> 6, lane = tid & 63, quad = lane >> 4, l16 = lane & 15;
  int m0, n0;
  xcd_tile(blockIdx.x, m0, n0);
  const int wm = wv & 1, wn = wv >> 1;

  floatx4 acc[4][2];
#pragma unroll
  for (int i = 0; i < 4; ++i)
#pragma unroll
    for (int j = 0; j < 2; ++j) acc[i][j] = (floatx4){0.f, 0.f, 0.f, 0.f};

  gemm_mainloop(A, Bw, As, Bs, m0, n0, wv, lane, acc);

  const int mb = m0 + wm * 64;
#pragma unroll
  for (int ni = 0; ni < 2; ++ni) {
    const int d = n0 + wn * 32 + ni * 16 + l16;
    const float bs = bo[d];
    float ps1 = 0.f, ps2 = 0.f;
#pragma unroll
    for (int mi = 0; mi < 4; ++mi)
#pragma unroll
      for (int r = 0; r < 4; ++r) {
        int m = mb + mi * 16 + quad * 4 + r;
        float val = acc[mi][ni][r] + bs + resid[(size_t)m * 1024 + d];
        y[(size_t)m * 1024 + d] = val;
        ps1 += val;
        ps2 += val * val;
      }
    ps1 += __shfl_xor(ps1, 16); ps1 += __shfl_xor(ps1, 32);
    ps2 += __shfl_xor(ps2, 16); ps2 += __shfl_xor(ps2, 32);
    if (quad == 0) {
      atomicAdd(&s1[d], ps1);
      atomicAdd(&s2[d], ps2);
    }
  }
}

// ---------------------------------------------------------------------------
// attn_k v9 (frozen at R10 state): swapped QK^T, cvt_pk pack, conflict-free
// P swizzle, ones-MFMA row-sum, single-slot P, per-rb register diet
// (live set ~112, VGPR 64, no spills), XCD-aware block decode.
// Known state: 93.5 us, 731 TF effective, FETCH 24.6 MB, occupancy 35%.
// LDS byte map: K dbuf [0,16384) | V dbuf [16384,32768) | P [32768,40960)
// ---------------------------------------------------------------------------
__global__ __launch_bounds__(256, 4) void attn_k(
    const ushort_t* __restrict__ q, const ushort_t* __restrict__ k,
    const ushort_t* __restrict__ vt, ushort_t* __restrict__ ao)
{
  __shared__ ushort_t lds[20480];   // 40 KiB
  char* ldsb = (char*)lds;
  const int tid = threadIdx.x;
  const int wv = tid >> 6, lane = tid & 63, quad = lane >> 4, l16 = lane & 15;

  const int id = blockIdx.x;
  const int j = id >> 3;
  const int pair = (id & 7) + 8 * (j >> 4);      // b*16 + h
  const int q0 = (j & 15) * 128;
  const int h = pair & 15, b = pair >> 4;

  const size_t bh = (size_t)(b * H_ + h) * S_;
  const ushort_t* vb = vt + (size_t)(b * H_ + h) * 64 * S_;

  short8 aq[2][2];
#pragma unroll
  for (int rb = 0; rb < 2; ++rb) {
    const ushort_t* qrow = q + (bh + q0 + wv * 32 + rb * 16 + l16) * 64;
    aq[rb][0] = *(const short8*)(qrow + quad * 8);
    aq[rb][1] = *(const short8*)(qrow + 32 + quad * 8);
  }

  short8 ones;
#pragma unroll
  for (int j2 = 0; j2 < 8; ++j2) ones[j2] = (short)0x3F80;

  floatx4 o[2][4];
  floatx4 accl[2];
#pragma unroll
  for (int rb = 0; rb < 2; ++rb) {
#pragma unroll
    for (int cb = 0; cb < 4; ++cb) o[rb][cb] = (floatx4){0.f, 0.f, 0.f, 0.f};
    accl[rb] = (floatx4){0.f, 0.f, 0.f, 0.f};
  }

  const int swz = ((l16 & 7) << 4) | (l16 & 8);
  const int q8 = quad * 8;
  const int pb = 32768 + wv * 2048 + l16 * 128;

  auto stage = [&](int nb, int t0) {
#pragma unroll
    for (int i = 0; i < 4; ++i) {
      const int idx = wv * 4 + i;
      const int cb = (idx >> 1) & 3, hf = idx & 1;
      if (idx < 8)
        gload16(k + (bh + t0 + cb * 16 + l16) * 64 + hf * 32 + quad * 8,
                (char*)lds + nb * 8192 + idx * 1024);
      else
        gload16(vb + (size_t)(cb * 16 + l16) * S_ + t0 + hf * 32 + quad * 8,
                (char*)lds + 16384 + nb * 8192 + (idx - 8) * 1024);
    }
  };

  stage(0, 0);
  asm volatile("s_waitcnt vmcnt(0)" ::: "memory");
  __syncthreads();

  for (int t0 = 0; t0 < S_; t0 += 64) {
    const int nb = (t0 >> 6) & 1;
    const ushort_t* KsC = lds + nb * 4096;
    const ushort_t* VsC = lds + 8192 + nb * 4096;
    if (t0 + 64 < S_) stage(nb ^ 1, t0 + 64);

    // per-rb: QK^T -> exp2 + pack -> P write -> PV  (single P slot; DS ops
    // are wave-in-order so rb1 writes cannot pass rb0 reads)
#pragma unroll
    for (int rb = 0; rb < 2; ++rb) {
      floatx4 sc[4];
#pragma unroll
      for (int cb = 0; cb < 4; ++cb) sc[cb] = (floatx4){0.f, 0.f, 0.f, 0.f};
      __builtin_amdgcn_s_setprio(1);
#pragma unroll
      for (int hf = 0; hf < 2; ++hf) {
        short8 bk[4];
#pragma unroll
        for (int cb = 0; cb < 4; ++cb)
          bk[cb] = *(const short8*)&KsC[(cb * 2 + hf) * 512 + lane * 8];
#pragma unroll
        for (int cb = 0; cb < 4; ++cb)
          sc[cb] = __builtin_amdgcn_mfma_f32_16x16x32_bf16(
              bk[cb], aq[rb][hf], sc[cb], 0, 0, 0);
      }
      __builtin_amdgcn_s_setprio(0);

#pragma unroll
      for (int cb = 0; cb < 4; ++cb) {
        float p0 = fast_exp2(sc[cb][0]);
        float p1 = fast_exp2(sc[cb][1]);
        float p2 = fast_exp2(sc[cb][2]);
        float p3 = fast_exp2(sc[cb][3]);
        uint2v w;
        w[0] = cvt_pk_bf16(p0, p1);
        w[1] = cvt_pk_bf16(p2, p3);
        *(uint2v*)(ldsb + pb + ((cb * 32 + q8) ^ swz)) = w;
      }
      asm volatile("s_waitcnt lgkmcnt(0)" ::: "memory");
      __builtin_amdgcn_sched_barrier(0);

      __builtin_amdgcn_s_setprio(1);
#pragma unroll
      for (int hf = 0; hf < 2; ++hf) {
        short8 bvf[4];
#pragma unroll
        for (int cb = 0; cb < 4; ++cb)
          bvf[cb] = *(const short8*)&VsC[(cb * 2 + hf) * 512 + lane * 8];
        const int lo = (hf * 64 + quad * 16) ^ swz;
        short4v a0 = *(const short4v*)(ldsb + pb + lo);
        short4v a1 = *(const short4v*)(ldsb + pb + (lo ^ 8));
        short8 ap;
        ap[0] = a0[0]; ap[1] = a0[1]; ap[2] = a0[2]; ap[3] = a0[3];
        ap[4] = a1[0]; ap[5] = a1[1]; ap[6] = a1[2]; ap[7] = a1[3];
#pragma unroll
        for (int cb = 0; cb < 4; ++cb)
          o[rb][cb] = __builtin_amdgcn_mfma_f32_16x16x32_bf16(
              ap, bvf[cb], o[rb][cb], 0, 0, 0);
        accl[rb] = __builtin_amdgcn_mfma_f32_16x16x32_bf16(
            ap, ones, accl[rb], 0, 0, 0);
      }
      __builtin_amdgcn_s_setprio(0);
    }

    asm volatile("s_waitcnt vmcnt(0)" ::: "memory");  // prefetch landed
    __syncthreads();
  }

  float linv[2][4];
#pragma unroll
  for (int rb = 0; rb < 2; ++rb)
#pragma unroll
    for (int r = 0; r < 4; ++r)
      linv[rb][r] = 1.f / accl[rb][r];
#pragma unroll
  for (int rb = 0; rb < 2; ++rb)
#pragma unroll
    for (int cb = 0; cb < 4; ++cb)
#pragma unroll
      for (int r = 0; r < 4; ++r) {
        float val = o[rb][cb][r] * linv[rb][r];
        size_t idx = (size_t)(b * S_ + q0 + wv * 32 + rb * 16 + quad * 4 + r) * 1024
                     + h * 64 + cb * 16 + l16;
        ao[idx] = f2bf(val);
      }
}

// ---------------------------------------------------------------------------
// K5: batchnorm affine + 64x64 transpose -> out[b][d][s] (f32)
// ---------------------------------------------------------------------------
__global__ __launch_bounds__(256) void norm_k(
    const float* __restrict__ y, const float* __restrict__ s1,
    const float* __restrict__ s2, const float* __restrict__ gamma,
    const float* __restrict__ beta, float* __restrict__ out)
{
  __shared__ float tile[64][65];
  __shared__ float scl[64], sft[64];
  const int tid = threadIdx.x;
  const int s0 = blockIdx.x * 64, d0 = blockIdx.y * 64, b = blockIdx.z;

  if (tid < 64) {
    int d = d0 + tid;
    float mean = s1[d] * (1.f / (float)NBS_);
    float var = s2[d] * (1.f / (float)NBS_) - mean * mean;
    float rstd = rsqrtf(var + EPS_);
    float g = gamma[d];
    scl[tid] = rstd * g;
    sft[tid] = beta[d] - mean * rstd * g;
  }
  __syncthreads();

  const int si = tid >> 2, dc = (tid & 3) * 16;
  const float* row = y + (size_t)(b * S_ + s0 + si) * D_ + d0 + dc;
#pragma unroll
  for (int j = 0; j < 16; ++j)
    tile[si][dc + j] = row[j] * scl[dc + j] + sft[dc + j];
  __syncthreads();

  const int di = tid >> 2, sg = (tid & 3) * 16;
  float* dst = out + (size_t)(b * D_ + d0 + di) * S_ + s0 + sg;
#pragma unroll
  for (int jj = 0; jj < 4; ++jj) {
    float4 p;
    p.x = tile[sg + jj * 4 + 0][di];
    p.y = tile[sg + jj * 4 + 1][di];
    p.z = tile[sg + jj * 4 + 2][di];
    p.w = tile[sg + jj * 4 + 3][di];
    *(float4*)(dst + jj * 4) = p;
  }
}

// ---------------------------------------------------------------------------
extern "C" void kernel_launch(void* const* d_in, const int* in_sizes, int n_in,
                              void* d_out, int out_size, void* d_ws, size_t ws_size,
                              hipStream_t stream)
{
  (void)in_sizes; (void)n_in; (void)out_size;
  const float* Q     = (const float*)d_in[0];
  const float* Kin   = (const float*)d_in[1];
  const float* Vin   = (const float*)d_in[2];
  const float* Wq    = (const float*)d_in[3];
  const float* bq    = (const float*)d_in[4];
  const float* Wk    = (const float*)d_in[5];
  const float* bk    = (const float*)d_in[6];
  const float* Wv    = (const float*)d_in[7];
  const float* bv    = (const float*)d_in[8];
  const float* Wo    = (const float*)d_in[9];
  const float* bo    = (const float*)d_in[10];
  const float* gamma = (const float*)d_in[11];
  const float* beta  = (const float*)d_in[12];
  float* out = (float*)d_out;

  char* ws = (char*)d_ws;
  const size_t MB = 1u << 20;
  ushort_t* xb  = (ushort_t*)(ws);               // xbQ in wide path
  ushort_t* wtq = (ushort_t*)(ws + 16 * MB);
  ushort_t* wtk = (ushort_t*)(ws + 18 * MB);
  ushort_t* wtv = (ushort_t*)(ws + 20 * MB);
  ushort_t* wto = (ushort_t*)(ws + 22 * MB);
  ushort_t* qb  = (ushort_t*)(ws + 24 * MB);
  ushort_t* kb  = (ushort_t*)(ws + 40 * MB);
  ushort_t* vtb = (ushort_t*)(ws + 56 * MB);
  ushort_t* xbK = (ushort_t*)(ws + 72 * MB);     // wide path only
  ushort_t* xbV = (ushort_t*)(ws + 88 * MB);     // wide path only
  ushort_t* ao  = (ushort_t*)(ws);
  float*    y   = (float*)(ws + 24 * MB);
  float*    s1  = (float*)(ws + 56 * MB);
  float*    s2  = (float*)(ws + 56 * MB + 4096);

  // all 4 weight transposes in one launch
  wtr_all<<<dim3(16, 16, 4), 256, 0, stream>>>(Wq, Wk, Wv, Wo,
                                               wtq, wtk, wtv, wto);

  // q pre-scaled by SCALE*log2(e) so attention logits are exp2-domain
  const float QSC = SCALE_ * 1.44269504088896f;

  if (ws_size >= 104 * MB) {
    // wide path: one cvtx launch (3 tensors), one projection launch (3 GEMMs)
    cvtx3_k<<<3 * 4096, 256, 0, stream>>>(Q, Kin, Vin, xb, xbK, xbV);
    gemm_proj3<<<3 * 512, 512, 0, stream>>>(xb, xbK, xbV, wtq, wtk, wtv,
                                            bq, bk, bv, qb, kb, vtb, QSC, 0);
  } else {
    // narrow fallback: single xb buffer, sequential (R10 scheme)
    cvtx3_k<<<4096, 256, 0, stream>>>(Q, Q, Q, xb, xb, xb);
    gemm_proj3<<<512, 512, 0, stream>>>(xb, xb, xb, wtq, wtk, wtv,
                                        bq, bk, bv, qb, kb, vtb, QSC, 0);
    cvtx3_k<<<4096, 256, 0, stream>>>(Kin, Kin, Kin, xb, xb, xb);
    gemm_proj3<<<512, 512, 0, stream>>>(xb, xb, xb, wtq, wtk, wtv,
                                        bq, bk, bv, qb, kb, vtb, QSC, 1);
    cvtx3_k<<<4096, 256, 0, stream>>>(Vin, Vin, Vin, xb, xb, xb);
    gemm_proj3<<<512, 512, 0, stream>>>(xb, xb, xb, wtq, wtk, wtv,
                                        bq, bk, bv, qb, kb, vtb, QSC, 2);
  }

  attn_k<<<1024, 256, 0, stream>>>(qb, kb, vtb, ao);

  // s1/s2 overlap vtb (dead after attn_k); zero them before fused oproj
  hipMemsetAsync(ws + 56 * MB, 0, 8192, stream);
  gemm_oproj<<<512, 512, 0, stream>>>(ao, wto, bo, Q, y, s1, s2);

  norm_k<<<dim3(32, 16, 4), 256, 0, stream>>>(y, s1, s2, gamma, beta, out);
}